// Round 3
// baseline (391.455 us; speedup 1.0000x reference)
//
#include <hip/hip_runtime.h>
#include <math.h>

// (B, N, IN, OUT, H, F) = (4, 2048, 128, 64, 4, 64)
#define BB   4
#define NN   2048
#define IND  128
#define CDIM 256          // H*OUT
#define NIT  16           // j-iterations of 128

typedef _Float16 half_t;
typedef _Float16 half4_t __attribute__((ext_vector_type(4)));
typedef _Float16 half8_t __attribute__((ext_vector_type(8)));
typedef float    f32x4   __attribute__((ext_vector_type(4)));

#define SHIFT 16.0f            // fixed softmax shift (S range ~[-24,24])
#define BSCL  6.103515625e-05f // 1/16384: u16 fixed-point step for fused bias
#define BOFF  (-17.5f)         // -1.5 (encode offset) - SHIFT

#define NPRE  (BB * NN / 8)    // 1024 precompute blocks
#define NFUSE 2048             // fuse-streaming blocks

// ---------------------------------------------------------------------------
// Kernel A (combined): blocks [0, NPRE) run per-row feature precompute
// (Q, K f16 + WhJ fragment-native tiles); blocks [NPRE, NPRE+NFUSE) stream
// the bias fusion bf = q16(pm + sm + qb) with perfectly coalesced loads.
// The fuse blocks are pure-BW; the pre blocks are VALU/LDS-heavy -> overlap.
// pm in [0,1), sm in (-1,1), |qb|<0.1 -> f in (-1.2,2.2) ⊂ (-1.5,2.5);
// u = rn((f+1.5)*16384); decode f-SHIFT = u*BSCL + BOFF.  (verified R1)
// ---------------------------------------------------------------------------
__global__ __launch_bounds__(256) void pre_fuse_kernel(
    const float* __restrict__ hg,   // (B*N, 128)
    const float* __restrict__ W,    // (128, 256)
    const float* __restrict__ R,    // (128, 64)
    const float* __restrict__ aq,   // (128, 64)
    const float* __restrict__ ak,   // (128, 64)
    const float* __restrict__ pm,   // (B,N,N)
    const float* __restrict__ sm,   // (B,N,N)
    const int*   __restrict__ qm,   // (B,N,N,2)
    const float* __restrict__ qbias,// (4,4)
    half_t* __restrict__ Qw,        // (B*N, 64) f16
    half_t* __restrict__ Kw,        // (B*N, 64) f16
    half_t* __restrict__ WhJ,       // (B, 128, 256, 16) f16 tiled
    unsigned short* __restrict__ bf)// (B,N,N) u16 fused bias
{
    const int tid = threadIdx.x;

    __shared__ float hs[8][IND];
    __shared__ float phis[8][IND];
    __shared__ float qbs[16];

    if (blockIdx.x >= NPRE) {
        // ---------------- fuse-streaming role ----------------
        if (tid < 16) qbs[tid] = qbias[tid];
        __syncthreads();
        const int nquad  = BB * NN * NN / 4;          // 4,194,304 quads
        const int stride = NFUSE * 256;
        for (int idx = (blockIdx.x - NPRE) * 256 + tid; idx < nquad; idx += stride) {
            const float4 p  = ((const float4*)pm)[idx];
            const float4 s  = ((const float4*)sm)[idx];
            const int4   qa = ((const int4*)qm)[(size_t)idx * 2];
            const int4   qb = ((const int4*)qm)[(size_t)idx * 2 + 1];
            const float f0 = p.x + s.x + qbs[(qa.x << 2) | qa.y];
            const float f1 = p.y + s.y + qbs[(qa.z << 2) | qa.w];
            const float f2 = p.z + s.z + qbs[(qb.x << 2) | qb.y];
            const float f3 = p.w + s.w + qbs[(qb.z << 2) | qb.w];
            const unsigned u0 = __float2uint_rn(fminf(fmaxf((f0 + 1.5f) * 16384.f, 0.f), 65535.f));
            const unsigned u1 = __float2uint_rn(fminf(fmaxf((f1 + 1.5f) * 16384.f, 0.f), 65535.f));
            const unsigned u2 = __float2uint_rn(fminf(fmaxf((f2 + 1.5f) * 16384.f, 0.f), 65535.f));
            const unsigned u3 = __float2uint_rn(fminf(fmaxf((f3 + 1.5f) * 16384.f, 0.f), 65535.f));
            uint2 o; o.x = u0 | (u1 << 16); o.y = u2 | (u3 << 16);
            ((uint2*)bf)[idx] = o;
        }
        return;
    }

    // ---------------- precompute role ----------------
    const int row0 = blockIdx.x * 8;

    {   // 8 rows x 128 = 256 float4
        const float4* src = (const float4*)(hg + (size_t)row0 * IND);
        ((float4*)&hs[0][0])[tid] = src[tid];
    }
    __syncthreads();

    {   // phi: f = tid&63, rr = tid>>6 in 0..3 -> rows rr, rr+4
        const int f  = tid & 63;
        const int rr = tid >> 6;
        float p0 = 0.f, p1 = 0.f;
        #pragma unroll 4
        for (int d0 = 0; d0 < IND; d0 += 4) {
            const float r0 = R[(d0 + 0) * 64 + f];
            const float r1 = R[(d0 + 1) * 64 + f];
            const float r2 = R[(d0 + 2) * 64 + f];
            const float r3 = R[(d0 + 3) * 64 + f];
            const float4 ha = *(const float4*)&hs[rr][d0];
            const float4 hb = *(const float4*)&hs[rr + 4][d0];
            p0 += ha.x * r0 + ha.y * r1 + ha.z * r2 + ha.w * r3;
            p1 += hb.x * r0 + hb.y * r1 + hb.z * r2 + hb.w * r3;
        }
        float s, c;
        __sincosf(p0, &s, &c); phis[rr][f]     = c; phis[rr][f + 64]     = s;
        __sincosf(p1, &s, &c); phis[rr + 4][f] = c; phis[rr + 4][f + 64] = s;
    }

    {   // Wh: thread owns column c = tid for the 8-row tile; store tiled f16.
        float acc[8];
        #pragma unroll
        for (int r = 0; r < 8; ++r) acc[r] = 0.f;
        #pragma unroll 2
        for (int d0 = 0; d0 < IND; d0 += 4) {
            const float w0 = W[(d0 + 0) * CDIM + tid];
            const float w1 = W[(d0 + 1) * CDIM + tid];
            const float w2 = W[(d0 + 2) * CDIM + tid];
            const float w3 = W[(d0 + 3) * CDIM + tid];
            #pragma unroll
            for (int r = 0; r < 8; ++r) {
                const float4 h4 = *(const float4*)&hs[r][d0];
                acc[r] += h4.x * w0 + h4.y * w1 + h4.z * w2 + h4.w * w3;
            }
        }
        const int b   = row0 >> 11;
        const int j16 = (row0 & (NN - 1)) >> 4;
        const int jr0 = row0 & 8;                  // 0 or 8 within the 16-tile
        half8_t v;
        #pragma unroll
        for (int r = 0; r < 8; ++r) v[r] = (half_t)acc[r];
        *(half8_t*)(WhJ + (((size_t)b * 128 + j16) * CDIM + tid) * 16 + jr0) = v;
    }
    __syncthreads();

    {   // Q/K: o = tid&63, qk bit selects aq/ak, rh = tid>>7 -> rows rh*4..+3
        const int o  = tid & 63;
        const int qk = (tid >> 6) & 1;
        const int rh = tid >> 7;
        const float* A = qk ? ak : aq;
        half_t*    Dst = qk ? Kw : Qw;
        float acc[4] = {0.f, 0.f, 0.f, 0.f};
        #pragma unroll 2
        for (int t0 = 0; t0 < IND; t0 += 4) {
            const float a0 = A[(t0 + 0) * 64 + o];
            const float a1 = A[(t0 + 1) * 64 + o];
            const float a2 = A[(t0 + 2) * 64 + o];
            const float a3 = A[(t0 + 3) * 64 + o];
            #pragma unroll
            for (int r = 0; r < 4; ++r) {
                const float4 ph = *(const float4*)&phis[rh * 4 + r][t0];
                acc[r] += ph.x * a0 + ph.y * a1 + ph.z * a2 + ph.w * a3;
            }
        }
        #pragma unroll
        for (int r = 0; r < 4; ++r)
            Dst[(size_t)(row0 + rh * 4 + r) * 64 + o] = (half_t)acc[r];
    }
}

// ---------------------------------------------------------------------------
// Kernel B (c-split, slim bias): wave w computes QK+softmax for j-stripe w
// and publishes P to LDS; after one raw barrier each wave runs PV over all
// 128 j for its own 32-column output slice. All per-iter loads are
// cache-resident: bW/K/Q in L2, fused bias bf (33 MB, just written) in L3.
// Bias = ONE uint2 per lane per iter, prefetched 2-deep; K 1-deep ping-pong.
// ---------------------------------------------------------------------------
#define ITERS(IT, KC0, KC1, KN0, KN1, UB, PB)                                   \
  {                                                                             \
    /* PV B-frags for this whole iteration: issue first, consume after bar */   \
    const half_t* wpt = wb + (size_t)(IT) * (8 * CDIM * 16);                    \
    half4_t bwv[16];                                                            \
    _Pragma("unroll")                                                           \
    for (int kk = 0; kk < 8; ++kk) {                                            \
      bwv[2 * kk]     = *(const half4_t*)(wpt + (size_t)kk * (CDIM * 16));      \
      bwv[2 * kk + 1] = *(const half4_t*)(wpt + (size_t)kk * (CDIM * 16) + 256);\
    }                                                                           \
    /* scores (transposed): S^T via A=K, B=Q */                                 \
    f32x4 s4 = (f32x4){0.f, 0.f, 0.f, 0.f};                                     \
    s4 = __builtin_amdgcn_mfma_f32_16x16x32_f16(KC0, qf0, s4, 0, 0, 0);         \
    s4 = __builtin_amdgcn_mfma_f32_16x16x32_f16(KC1, qf1, s4, 0, 0, 0);         \
    if ((IT) + 1 < NIT) {                                                       \
      const half_t* kp = kbase + (size_t)((IT) + 1) * 128 * 64;                 \
      KN0 = *(const half8_t*)(kp + q * 8);                                      \
      KN1 = *(const half8_t*)(kp + 32 + q * 8);                                 \
    }                                                                           \
    const uint2 uc = UB;                                                        \
    if ((IT) + 2 < NIT)                                                         \
      UB = *(const uint2*)(bfr + (size_t)((IT) + 2) * 128 + cbase);             \
    const float sv0 = s4[0] + fmaf((float)(uc.x & 0xffffu), BSCL, BOFF);        \
    const float sv1 = s4[1] + fmaf((float)(uc.x >> 16),     BSCL, BOFF);        \
    const float sv2 = s4[2] + fmaf((float)(uc.y & 0xffffu), BSCL, BOFF);        \
    const float sv3 = s4[3] + fmaf((float)(uc.y >> 16),     BSCL, BOFF);        \
    const half_t h0 = (half_t)__expf(fminf(sv0, 11.f));                         \
    const half_t h1 = (half_t)__expf(fminf(sv1, 11.f));                         \
    const half_t h2 = (half_t)__expf(fminf(sv2, 11.f));                         \
    const half_t h3 = (half_t)__expf(fminf(sv3, 11.f));                         \
    half4_t aP; aP[0] = h0; aP[1] = h1; aP[2] = h2; aP[3] = h3;                 \
    lacc += (float)h0 + (float)h1 + (float)h2 + (float)h3;                      \
    *(half4_t*)&Pl[PB][w][lane * 4] = aP;                                       \
    asm volatile("s_waitcnt lgkmcnt(0)" ::: "memory");                          \
    __builtin_amdgcn_s_barrier();                                               \
    asm volatile("" ::: "memory");                                              \
    /* PV: O[i][c] for this wave's 32 cols, k over all 8 stripes */             \
    _Pragma("unroll")                                                           \
    for (int kk = 0; kk < 8; ++kk) {                                            \
      const half4_t pa = *(const half4_t*)&Pl[PB][kk][lane * 4];                \
      acc0 = __builtin_amdgcn_mfma_f32_16x16x16f16(pa, bwv[2 * kk],     acc0, 0, 0, 0); \
      acc1 = __builtin_amdgcn_mfma_f32_16x16x16f16(pa, bwv[2 * kk + 1], acc1, 0, 0, 0); \
    }                                                                           \
  }

__global__ __launch_bounds__(512, 4) void attn4s_kernel(
    const half_t* __restrict__ Qw, const half_t* __restrict__ Kw,
    const half_t* __restrict__ WhJ,
    const unsigned short* __restrict__ bf,   // (B,N,N) fused bias u16
    const float* __restrict__ op,            // (256,64) f32
    float* __restrict__ out)                 // (B*N, 64)
{
    const int tid  = threadIdx.x;
    const int w    = tid >> 6;         // j-stripe for QK, 32-col slice for PV
    const int lane = tid & 63;
    const int n    = lane & 15;
    const int q    = lane >> 4;

    const int blk = blockIdx.x;
    const int b   = (blk & 7) >> 1;    // XCD swizzle: one batch per XCD pair
    const int i0  = (((blk >> 3) << 1) | (blk & 1)) * 16;

    __shared__ __align__(16) half_t Pl[2][8][256];   // [buf][stripe][lane*4]
    __shared__ __align__(16) float  BufT0[CDIM][20]; // O, transposed [c][row]
    __shared__ float Lp[8][16];

    // persistent Q B-frag: B[k][n] = Q[i0+n][k]
    const half_t* qptr = Qw + ((size_t)(b * NN) + i0 + n) * 64;
    const half8_t qf0 = *(const half8_t*)(qptr + q * 8);
    const half8_t qf1 = *(const half8_t*)(qptr + 32 + q * 8);

    // fused bias: row i = i0+n, cols j = it*128 + w*16 + q*4 + r
    const size_t rowoff = ((size_t)b * NN + i0 + n) * NN;
    const unsigned short* bfr = bf + rowoff;
    const int cbase = w * 16 + q * 4;

    // K A-frag base: A[m=jr][k] = K[it*128 + w*16 + n][k]
    const half_t* kbase = Kw + ((size_t)b * NN + w * 16 + n) * 64;
    // PV B-frag base: wave w's cols w*32..w*32+31
    const half_t* wb = WhJ + ((size_t)b * 128 * CDIM + (size_t)(w * 32 + n)) * 16 + q * 4;

    // prologue prefetch: bias 2-deep, K 1-deep ping-pong
    uint2 ub0 = *(const uint2*)(bfr + cbase);
    uint2 ub1 = *(const uint2*)(bfr + 128 + cbase);
    half8_t ka0 = *(const half8_t*)(kbase + q * 8);
    half8_t ka1 = *(const half8_t*)(kbase + 32 + q * 8);
    half8_t kb0 = ka0, kb1 = ka1;

    f32x4 acc0 = (f32x4){0.f, 0.f, 0.f, 0.f};
    f32x4 acc1 = (f32x4){0.f, 0.f, 0.f, 0.f};
    float lacc = 0.f;

    for (int it = 0; it < NIT; it += 2) {
        ITERS(it,     ka0, ka1, kb0, kb1, ub0, 0)
        ITERS(it + 1, kb0, kb1, ka0, ka1, ub1, 1)
    }

    // ---- row-l partials ----
    lacc += __shfl_xor(lacc, 16);
    lacc += __shfl_xor(lacc, 32);
    if (lane < 16) Lp[w][lane] = lacc;

    // ---- each wave stores its own final 32 columns ----
    *(f32x4*)&BufT0[w * 32 + n][q * 4]      = acc0;
    *(f32x4*)&BufT0[w * 32 + 16 + n][q * 4] = acc1;
    __syncthreads();

    // ---- projection + ELU: wave w -> rows 2w, 2w+1 ; lane -> col o ----
    {
        const int r0 = 2 * w, r1 = 2 * w + 1;
        float pacc0 = 0.f, pacc1 = 0.f;
        #pragma unroll 8
        for (int c = 0; c < CDIM; ++c) {
            const float wv = op[c * 64 + lane];     // coalesced, L2-resident
            pacc0 += BufT0[c][r0] * wv;             // LDS broadcast
            pacc1 += BufT0[c][r1] * wv;
        }
        float lt0 = 0.f, lt1 = 0.f;
        #pragma unroll
        for (int gg = 0; gg < 8; ++gg) { lt0 += Lp[gg][r0]; lt1 += Lp[gg][r1]; }
        float x0 = pacc0 / lt0;
        float x1 = pacc1 / lt1;
        x0 = x0 > 0.f ? x0 : (__expf(x0) - 1.f);
        x1 = x1 > 0.f ? x1 : (__expf(x1) - 1.f);
        out[((size_t)b * NN + i0 + r0) * 64 + lane] = x0;
        out[((size_t)b * NN + i0 + r1) * 64 + lane] = x1;
    }
}

// ---------------------------------------------------------------------------
// Fallback: full-bias attn4 (R2-verified) if workspace can't hold bf.
// ---------------------------------------------------------------------------
#define ITERF(IT, KC0, KC1, KN0, KN1, PB)                                       \
  {                                                                             \
    const half_t* wpt = wb + (size_t)(IT) * (8 * CDIM * 16);                    \
    half4_t bwv[16];                                                            \
    _Pragma("unroll")                                                           \
    for (int kk = 0; kk < 8; ++kk) {                                            \
      bwv[2 * kk]     = *(const half4_t*)(wpt + (size_t)kk * (CDIM * 16));      \
      bwv[2 * kk + 1] = *(const half4_t*)(wpt + (size_t)kk * (CDIM * 16) + 256);\
    }                                                                           \
    f32x4 s4 = (f32x4){0.f, 0.f, 0.f, 0.f};                                     \
    s4 = __builtin_amdgcn_mfma_f32_16x16x32_f16(KC0, qf0, s4, 0, 0, 0);         \
    s4 = __builtin_amdgcn_mfma_f32_16x16x32_f16(KC1, qf1, s4, 0, 0, 0);         \
    if ((IT) + 1 < NIT) {                                                       \
      const half_t* kp = kbase + (size_t)((IT) + 1) * 128 * 64;                 \
      KN0 = *(const half8_t*)(kp + q * 8);                                      \
      KN1 = *(const half8_t*)(kp + 32 + q * 8);                                 \
    }                                                                           \
    const float4 pmC = pmN; const float4 smC = smN;                             \
    const int4 qA = qmN0;  const int4 qB = qmN1;                                \
    if ((IT) + 1 < NIT) {                                                       \
      const int jn = ((IT) + 1) * 128 + cbase;                                  \
      pmN  = *(const float4*)(pmr + jn);                                        \
      smN  = *(const float4*)(smr + jn);                                        \
      qmN0 = *(const int4*)(qmr + (size_t)jn * 2);                              \
      qmN1 = *(const int4*)(qmr + (size_t)jn * 2 + 4);                          \
    }                                                                           \
    const float sv0 = s4[0] + pmC.x + smC.x + qbs[qA.x * 4 + qA.y];             \
    const float sv1 = s4[1] + pmC.y + smC.y + qbs[qA.z * 4 + qA.w];             \
    const float sv2 = s4[2] + pmC.z + smC.z + qbs[qB.x * 4 + qB.y];             \
    const float sv3 = s4[3] + pmC.w + smC.w + qbs[qB.z * 4 + qB.w];             \
    const half_t h0 = (half_t)__expf(fminf(sv0, 11.f));                         \
    const half_t h1 = (half_t)__expf(fminf(sv1, 11.f));                         \
    const half_t h2 = (half_t)__expf(fminf(sv2, 11.f));                         \
    const half_t h3 = (half_t)__expf(fminf(sv3, 11.f));                         \
    half4_t aP; aP[0] = h0; aP[1] = h1; aP[2] = h2; aP[3] = h3;                 \
    lacc += (float)h0 + (float)h1 + (float)h2 + (float)h3;                      \
    *(half4_t*)&Pl[PB][w][lane * 4] = aP;                                       \
    asm volatile("s_waitcnt lgkmcnt(0)" ::: "memory");                          \
    __builtin_amdgcn_s_barrier();                                               \
    asm volatile("" ::: "memory");                                              \
    _Pragma("unroll")                                                           \
    for (int kk = 0; kk < 8; ++kk) {                                            \
      const half4_t pa = *(const half4_t*)&Pl[PB][kk][lane * 4];                \
      acc0 = __builtin_amdgcn_mfma_f32_16x16x16f16(pa, bwv[2 * kk],     acc0, 0, 0, 0); \
      acc1 = __builtin_amdgcn_mfma_f32_16x16x16f16(pa, bwv[2 * kk + 1], acc1, 0, 0, 0); \
    }                                                                           \
  }

__global__ __launch_bounds__(512, 4) void attn4_kernel(
    const half_t* __restrict__ Qw, const half_t* __restrict__ Kw,
    const half_t* __restrict__ WhJ,
    const float* __restrict__ pm, const float* __restrict__ sm,
    const int*   __restrict__ qm, const float* __restrict__ qbias,
    const float* __restrict__ op, float* __restrict__ out)
{
    const int tid  = threadIdx.x;
    const int w    = tid >> 6;
    const int lane = tid & 63;
    const int n    = lane & 15;
    const int q    = lane >> 4;

    const int blk = blockIdx.x;
    const int b   = (blk & 7) >> 1;
    const int i0  = (((blk >> 3) << 1) | (blk & 1)) * 16;

    __shared__ __align__(16) half_t Pl[2][8][256];
    __shared__ __align__(16) float  BufT0[CDIM][20];
    __shared__ float Lp[8][16];
    __shared__ float qbs[16];

    if (tid < 16) qbs[tid] = qbias[tid] - SHIFT;
    __syncthreads();

    const half_t* qptr = Qw + ((size_t)(b * NN) + i0 + n) * 64;
    const half8_t qf0 = *(const half8_t*)(qptr + q * 8);
    const half8_t qf1 = *(const half8_t*)(qptr + 32 + q * 8);

    const size_t rowoff = ((size_t)b * NN + i0 + n) * NN;
    const float* pmr = pm + rowoff;
    const float* smr = sm + rowoff;
    const int*   qmr = qm + rowoff * 2;
    const int cbase = w * 16 + q * 4;

    const half_t* kbase = Kw + ((size_t)b * NN + w * 16 + n) * 64;
    const half_t* wb = WhJ + ((size_t)b * 128 * CDIM + (size_t)(w * 32 + n)) * 16 + q * 4;

    float4 pmN  = *(const float4*)(pmr + cbase);
    float4 smN  = *(const float4*)(smr + cbase);
    int4   qmN0 = *(const int4*)(qmr + cbase * 2);
    int4   qmN1 = *(const int4*)(qmr + cbase * 2 + 4);
    half8_t ka0 = *(const half8_t*)(kbase + q * 8);
    half8_t ka1 = *(const half8_t*)(kbase + 32 + q * 8);
    half8_t kb0 = ka0, kb1 = ka1;

    f32x4 acc0 = (f32x4){0.f, 0.f, 0.f, 0.f};
    f32x4 acc1 = (f32x4){0.f, 0.f, 0.f, 0.f};
    float lacc = 0.f;

    for (int it = 0; it < NIT; it += 2) {
        ITERF(it,     ka0, ka1, kb0, kb1, 0)
        ITERF(it + 1, kb0, kb1, ka0, ka1, 1)
    }

    lacc += __shfl_xor(lacc, 16);
    lacc += __shfl_xor(lacc, 32);
    if (lane < 16) Lp[w][lane] = lacc;

    *(f32x4*)&BufT0[w * 32 + n][q * 4]      = acc0;
    *(f32x4*)&BufT0[w * 32 + 16 + n][q * 4] = acc1;
    __syncthreads();

    {
        const int r0 = 2 * w, r1 = 2 * w + 1;
        float pacc0 = 0.f, pacc1 = 0.f;
        #pragma unroll 8
        for (int c = 0; c < CDIM; ++c) {
            const float wv = op[c * 64 + lane];
            pacc0 += BufT0[c][r0] * wv;
            pacc1 += BufT0[c][r1] * wv;
        }
        float lt0 = 0.f, lt1 = 0.f;
        #pragma unroll
        for (int gg = 0; gg < 8; ++gg) { lt0 += Lp[gg][r0]; lt1 += Lp[gg][r1]; }
        float x0 = pacc0 / lt0;
        float x1 = pacc1 / lt1;
        x0 = x0 > 0.f ? x0 : (__expf(x0) - 1.f);
        x1 = x1 > 0.f ? x1 : (__expf(x1) - 1.f);
        out[((size_t)b * NN + i0 + r0) * 64 + lane] = x0;
        out[((size_t)b * NN + i0 + r1) * 64 + lane] = x1;
    }
}

// ---------------------------------------------------------------------------
extern "C" void kernel_launch(void* const* d_in, const int* in_sizes, int n_in,
                              void* d_out, int out_size, void* d_ws, size_t ws_size,
                              hipStream_t stream) {
    (void)in_sizes; (void)n_in; (void)out_size;
    const float* h  = (const float*)d_in[0];
    const float* pm = (const float*)d_in[1];
    const float* sm = (const float*)d_in[2];
    const float* W  = (const float*)d_in[3];
    const float* R  = (const float*)d_in[4];
    const float* aq = (const float*)d_in[5];
    const float* ak = (const float*)d_in[6];
    const float* qb = (const float*)d_in[7];
    const float* op = (const float*)d_in[8];
    const int*   qm = (const int*)d_in[9];
    float* out = (float*)d_out;

    half_t* ws  = (half_t*)d_ws;
    half_t* Qw  = ws;                                 // 1 MB
    half_t* Kw  = ws + (size_t)BB * NN * 64;          // 1 MB
    half_t* WhJ = ws + (size_t)BB * NN * 64 * 2;      // 4 MB
    unsigned short* bf =
        (unsigned short*)(ws + (size_t)BB * NN * 64 * 2 + (size_t)BB * NN * CDIM); // 33.5 MB

    const size_t need = ((size_t)BB * NN * 64 * 2 + (size_t)BB * NN * CDIM) * sizeof(half_t)
                      + (size_t)BB * NN * NN * sizeof(unsigned short);

    if (ws_size >= need) {
        pre_fuse_kernel<<<NPRE + NFUSE, 256, 0, stream>>>(
            h, W, R, aq, ak, pm, sm, qm, qb, Qw, Kw, WhJ, bf);
        attn4s_kernel<<<BB * (NN / 16), 512, 0, stream>>>(Qw, Kw, WhJ, bf, op, out);
    } else {
        pre_fuse_kernel<<<NPRE, 256, 0, stream>>>(
            h, W, R, aq, ak, pm, sm, qm, qb, Qw, Kw, WhJ, bf);
        attn4_kernel<<<BB * (NN / 16), 512, 0, stream>>>(Qw, Kw, WhJ, pm, sm, qm, qb, op, out);
    }
}

// Round 4
// 337.746 us; speedup vs baseline: 1.1590x; 1.1590x over previous
//
#include <hip/hip_runtime.h>
#include <math.h>

// (B, N, IN, OUT, H, F) = (4, 2048, 128, 64, 4, 64)
#define BB   4
#define NN   2048
#define IND  128
#define CDIM 256          // H*OUT
#define NIT  16           // j-iterations of 128

typedef _Float16 half_t;
typedef _Float16 half4_t __attribute__((ext_vector_type(4)));
typedef _Float16 half8_t __attribute__((ext_vector_type(8)));
typedef float    f32x4   __attribute__((ext_vector_type(4)));

#define SHIFT 16.0f   // fixed softmax shift (S range ~[-24,24]); clamp guards f16

// ---------------------------------------------------------------------------
// Kernel A: per-row features -> f16 Q, K (row-major) and WhJ fragment-native
// tiles (B, 128, 256, 16): Wh[j16*16+jr][c] at ((b*128+j16)*256+c)*16+jr.
// (standalone again -- R3 showed merging roles into one dispatch serializes
//  the BW role behind the VALU role)
// ---------------------------------------------------------------------------
__global__ __launch_bounds__(256) void precompute_kernel(
    const float* __restrict__ hg,   // (B*N, 128)
    const float* __restrict__ W,    // (128, 256)
    const float* __restrict__ R,    // (128, 64)
    const float* __restrict__ aq,   // (128, 64)
    const float* __restrict__ ak,   // (128, 64)
    half_t* __restrict__ Qw,        // (B*N, 64) f16
    half_t* __restrict__ Kw,        // (B*N, 64) f16
    half_t* __restrict__ WhJ)       // (B, 128, 256, 16) f16 tiled
{
    const int tid  = threadIdx.x;
    const int row0 = blockIdx.x * 8;

    __shared__ float hs[8][IND];
    __shared__ float phis[8][IND];

    {   // 8 rows x 128 = 256 float4
        const float4* src = (const float4*)(hg + (size_t)row0 * IND);
        ((float4*)&hs[0][0])[tid] = src[tid];
    }
    __syncthreads();

    {   // phi: f = tid&63, rr = tid>>6 in 0..3 -> rows rr, rr+4
        const int f  = tid & 63;
        const int rr = tid >> 6;
        float p0 = 0.f, p1 = 0.f;
        #pragma unroll 4
        for (int d0 = 0; d0 < IND; d0 += 4) {
            const float r0 = R[(d0 + 0) * 64 + f];
            const float r1 = R[(d0 + 1) * 64 + f];
            const float r2 = R[(d0 + 2) * 64 + f];
            const float r3 = R[(d0 + 3) * 64 + f];
            const float4 ha = *(const float4*)&hs[rr][d0];
            const float4 hb = *(const float4*)&hs[rr + 4][d0];
            p0 += ha.x * r0 + ha.y * r1 + ha.z * r2 + ha.w * r3;
            p1 += hb.x * r0 + hb.y * r1 + hb.z * r2 + hb.w * r3;
        }
        float s, c;
        __sincosf(p0, &s, &c); phis[rr][f]     = c; phis[rr][f + 64]     = s;
        __sincosf(p1, &s, &c); phis[rr + 4][f] = c; phis[rr + 4][f + 64] = s;
    }

    {   // Wh: thread owns column c = tid for the 8-row tile; store tiled f16.
        float acc[8];
        #pragma unroll
        for (int r = 0; r < 8; ++r) acc[r] = 0.f;
        #pragma unroll 2
        for (int d0 = 0; d0 < IND; d0 += 4) {
            const float w0 = W[(d0 + 0) * CDIM + tid];
            const float w1 = W[(d0 + 1) * CDIM + tid];
            const float w2 = W[(d0 + 2) * CDIM + tid];
            const float w3 = W[(d0 + 3) * CDIM + tid];
            #pragma unroll
            for (int r = 0; r < 8; ++r) {
                const float4 h4 = *(const float4*)&hs[r][d0];
                acc[r] += h4.x * w0 + h4.y * w1 + h4.z * w2 + h4.w * w3;
            }
        }
        const int b   = row0 >> 11;
        const int j16 = (row0 & (NN - 1)) >> 4;
        const int jr0 = row0 & 8;                  // 0 or 8 within the 16-tile
        half8_t v;
        #pragma unroll
        for (int r = 0; r < 8; ++r) v[r] = (half_t)acc[r];
        *(half8_t*)(WhJ + (((size_t)b * 128 + j16) * CDIM + tid) * 16 + jr0) = v;
    }
    __syncthreads();

    {   // Q/K: o = tid&63, qk bit selects aq/ak, rh = tid>>7 -> rows rh*4..+3
        const int o  = tid & 63;
        const int qk = (tid >> 6) & 1;
        const int rh = tid >> 7;
        const float* A = qk ? ak : aq;
        half_t*    Dst = qk ? Kw : Qw;
        float acc[4] = {0.f, 0.f, 0.f, 0.f};
        #pragma unroll 2
        for (int t0 = 0; t0 < IND; t0 += 4) {
            const float a0 = A[(t0 + 0) * 64 + o];
            const float a1 = A[(t0 + 1) * 64 + o];
            const float a2 = A[(t0 + 2) * 64 + o];
            const float a3 = A[(t0 + 3) * 64 + o];
            #pragma unroll
            for (int r = 0; r < 4; ++r) {
                const float4 ph = *(const float4*)&phis[rh * 4 + r][t0];
                acc[r] += ph.x * a0 + ph.y * a1 + ph.z * a2 + ph.w * a3;
            }
        }
        #pragma unroll
        for (int r = 0; r < 4; ++r)
            Dst[(size_t)(row0 + rh * 4 + r) * 64 + o] = (half_t)acc[r];
    }
}

// ---------------------------------------------------------------------------
// Kernel B (attn5): c-split flash attention with COALESCED LDS-staged bias.
// Per iteration the block needs bias tile rows i0..i0+15, cols it*128..+127
// (pm 8K + sm 8K + qm 16K = 32 KB). Thread t loads row t>>5, cols (t&31)*4:
// every 32-thread group reads 512B-1KB CONTIGUOUS (vs 64B granule before,
// which measured 1.2 TB/s). Tiles convert to fused f16 bias in registers and
// publish to double-buffered Bl one iteration ahead; the existing single
// per-iteration barrier (P exchange) provides the one stage of separation
// double-buffering needs -- no extra barriers.
//   stage it:  reads Bl[it&1] (+Pl[it&1] post-bar), writes Bl[1-(it&1)]
// ---------------------------------------------------------------------------
#define ITER5(IT, KC0, KC1, KN0, KN1, PB)                                       \
  {                                                                             \
    /* PV B-frags for this whole iteration: issue first, consume after bar */   \
    const half_t* wpt = wb + (size_t)(IT) * (8 * CDIM * 16);                    \
    half4_t bwv[16];                                                            \
    _Pragma("unroll")                                                           \
    for (int kk = 0; kk < 8; ++kk) {                                            \
      bwv[2 * kk]     = *(const half4_t*)(wpt + (size_t)kk * (CDIM * 16));      \
      bwv[2 * kk + 1] = *(const half4_t*)(wpt + (size_t)kk * (CDIM * 16) + 256);\
    }                                                                           \
    /* publish next tile's fused bias (regs loaded one iteration ago) */        \
    if ((IT) + 1 < NIT) {                                                       \
      half4_t hb;                                                               \
      hb[0] = (half_t)(pmv.x + smv.x + qbs[(qiv0.x << 2) | qiv0.y]);            \
      hb[1] = (half_t)(pmv.y + smv.y + qbs[(qiv0.z << 2) | qiv0.w]);            \
      hb[2] = (half_t)(pmv.z + smv.z + qbs[(qiv1.x << 2) | qiv1.y]);            \
      hb[3] = (half_t)(pmv.w + smv.w + qbs[(qiv1.z << 2) | qiv1.w]);            \
      *(half4_t*)&Bl[1 - (PB)][str][stc] = hb;                                  \
    }                                                                           \
    /* issue coalesced bias loads for tile IT+2 */                              \
    if ((IT) + 2 < NIT) {                                                       \
      pmv  = *(const float4*)(pmt + ((IT) + 2) * 128);                          \
      smv  = *(const float4*)(smt + ((IT) + 2) * 128);                          \
      qiv0 = *(const int4*)(qmt + (size_t)((IT) + 2) * 256);                    \
      qiv1 = *(const int4*)(qmt + (size_t)((IT) + 2) * 256 + 4);                \
    }                                                                           \
    /* scores (transposed): S^T via A=K, B=Q */                                 \
    f32x4 s4 = (f32x4){0.f, 0.f, 0.f, 0.f};                                     \
    s4 = __builtin_amdgcn_mfma_f32_16x16x32_f16(KC0, qf0, s4, 0, 0, 0);         \
    s4 = __builtin_amdgcn_mfma_f32_16x16x32_f16(KC1, qf1, s4, 0, 0, 0);         \
    if ((IT) + 1 < NIT) {                                                       \
      const half_t* kp = kbase + (size_t)((IT) + 1) * 128 * 64;                 \
      KN0 = *(const half8_t*)(kp + q * 8);                                      \
      KN1 = *(const half8_t*)(kp + 32 + q * 8);                                 \
    }                                                                           \
    /* bias from LDS (written last iter, synced by last iter's barrier) */      \
    const half4_t bh = *(const half4_t*)&Bl[PB][n][cbase];                      \
    const float sv0 = s4[0] + (float)bh[0] - SHIFT;                             \
    const float sv1 = s4[1] + (float)bh[1] - SHIFT;                             \
    const float sv2 = s4[2] + (float)bh[2] - SHIFT;                             \
    const float sv3 = s4[3] + (float)bh[3] - SHIFT;                             \
    const half_t h0 = (half_t)__expf(fminf(sv0, 11.f));                         \
    const half_t h1 = (half_t)__expf(fminf(sv1, 11.f));                         \
    const half_t h2 = (half_t)__expf(fminf(sv2, 11.f));                         \
    const half_t h3 = (half_t)__expf(fminf(sv3, 11.f));                         \
    half4_t aP; aP[0] = h0; aP[1] = h1; aP[2] = h2; aP[3] = h3;                 \
    lacc += (float)h0 + (float)h1 + (float)h2 + (float)h3;                      \
    *(half4_t*)&Pl[PB][w][lane * 4] = aP;                                       \
    asm volatile("s_waitcnt lgkmcnt(0)" ::: "memory");                          \
    __builtin_amdgcn_s_barrier();                                               \
    asm volatile("" ::: "memory");                                              \
    /* PV: O[i][c] for this wave's 32 cols, k over all 8 stripes */             \
    _Pragma("unroll")                                                           \
    for (int kk = 0; kk < 8; ++kk) {                                            \
      const half4_t pa = *(const half4_t*)&Pl[PB][kk][lane * 4];                \
      acc0 = __builtin_amdgcn_mfma_f32_16x16x16f16(pa, bwv[2 * kk],     acc0, 0, 0, 0); \
      acc1 = __builtin_amdgcn_mfma_f32_16x16x16f16(pa, bwv[2 * kk + 1], acc1, 0, 0, 0); \
    }                                                                           \
  }

__global__ __launch_bounds__(512, 4) void attn5_kernel(
    const half_t* __restrict__ Qw, const half_t* __restrict__ Kw,
    const half_t* __restrict__ WhJ,
    const float* __restrict__ pm,      // (B,N,N)
    const float* __restrict__ sm,      // (B,N,N)
    const int*   __restrict__ qm,      // (B,N,N,2)
    const float* __restrict__ qbias,   // (4,4)
    const float* __restrict__ op,      // (256,64) f32
    float* __restrict__ out)           // (B*N, 64)
{
    const int tid  = threadIdx.x;
    const int w    = tid >> 6;         // j-stripe for QK, 32-col slice for PV
    const int lane = tid & 63;
    const int n    = lane & 15;
    const int q    = lane >> 4;

    const int blk = blockIdx.x;
    const int b   = (blk & 7) >> 1;    // XCD swizzle: one batch per XCD pair
    const int i0  = (((blk >> 3) << 1) | (blk & 1)) * 16;

    __shared__ __align__(16) half_t Pl[2][8][256];   // [buf][stripe][lane*4]
    __shared__ __align__(16) half_t Bl[2][16][132];  // [buf][row][col] fused bias
    __shared__ __align__(16) float  BufT0[CDIM][20]; // O, transposed [c][row]
    __shared__ float Lp[8][16];
    __shared__ float qbs[16];

    if (tid < 16) qbs[tid] = qbias[tid];

    // persistent Q B-frag: B[k][n] = Q[i0+n][k]
    const half_t* qptr = Qw + ((size_t)(b * NN) + i0 + n) * 64;
    const half8_t qf0 = *(const half8_t*)(qptr + q * 8);
    const half8_t qf1 = *(const half8_t*)(qptr + 32 + q * 8);

    // cooperative bias staging: thread -> row str = tid>>5, cols stc..stc+3
    const int str = tid >> 5;
    const int stc = (tid & 31) * 4;
    const float* pmt = pm + ((size_t)b * NN + i0 + str) * NN + stc;
    const float* smt = sm + ((size_t)b * NN + i0 + str) * NN + stc;
    const int*   qmt = qm + (((size_t)b * NN + i0 + str) * NN + stc) * 2;

    // softmax consumer: row n, cols cbase..cbase+3 of the staged tile
    const int cbase = w * 16 + q * 4;

    // K A-frag base: A[m=jr][k] = K[it*128 + w*16 + n][k]
    const half_t* kbase = Kw + ((size_t)b * NN + w * 16 + n) * 64;
    // PV B-frag base: wave w's cols w*32..w*32+31
    const half_t* wb = WhJ + ((size_t)b * 128 * CDIM + (size_t)(w * 32 + n)) * 16 + q * 4;

    // ---- prologue: tile0 -> Bl[0]; tile1 -> regs; K 1-deep ping-pong ----
    float4 pmv  = *(const float4*)(pmt);
    float4 smv  = *(const float4*)(smt);
    int4   qiv0 = *(const int4*)(qmt);
    int4   qiv1 = *(const int4*)(qmt + 4);
    half8_t ka0 = *(const half8_t*)(kbase + q * 8);
    half8_t ka1 = *(const half8_t*)(kbase + 32 + q * 8);
    half8_t kb0 = ka0, kb1 = ka1;
    __syncthreads();   // qbs ready
    {
        half4_t hb;
        hb[0] = (half_t)(pmv.x + smv.x + qbs[(qiv0.x << 2) | qiv0.y]);
        hb[1] = (half_t)(pmv.y + smv.y + qbs[(qiv0.z << 2) | qiv0.w]);
        hb[2] = (half_t)(pmv.z + smv.z + qbs[(qiv1.x << 2) | qiv1.y]);
        hb[3] = (half_t)(pmv.w + smv.w + qbs[(qiv1.z << 2) | qiv1.w]);
        *(half4_t*)&Bl[0][str][stc] = hb;
    }
    pmv  = *(const float4*)(pmt + 128);
    smv  = *(const float4*)(smt + 128);
    qiv0 = *(const int4*)(qmt + 256);
    qiv1 = *(const int4*)(qmt + 256 + 4);
    __syncthreads();   // Bl[0] visible

    f32x4 acc0 = (f32x4){0.f, 0.f, 0.f, 0.f};
    f32x4 acc1 = (f32x4){0.f, 0.f, 0.f, 0.f};
    float lacc = 0.f;

    for (int it = 0; it < NIT; it += 2) {
        ITER5(it,     ka0, ka1, kb0, kb1, 0)
        ITER5(it + 1, kb0, kb1, ka0, ka1, 1)
    }

    // ---- row-l partials ----
    lacc += __shfl_xor(lacc, 16);
    lacc += __shfl_xor(lacc, 32);
    if (lane < 16) Lp[w][lane] = lacc;

    // ---- each wave stores its own final 32 columns ----
    *(f32x4*)&BufT0[w * 32 + n][q * 4]      = acc0;
    *(f32x4*)&BufT0[w * 32 + 16 + n][q * 4] = acc1;
    __syncthreads();

    // ---- projection + ELU: wave w -> rows 2w, 2w+1 ; lane -> col o ----
    {
        const int r0 = 2 * w, r1 = 2 * w + 1;
        float pacc0 = 0.f, pacc1 = 0.f;
        #pragma unroll 8
        for (int c = 0; c < CDIM; ++c) {
            const float wv = op[c * 64 + lane];     // coalesced, L2-resident
            pacc0 += BufT0[c][r0] * wv;             // LDS broadcast
            pacc1 += BufT0[c][r1] * wv;
        }
        float lt0 = 0.f, lt1 = 0.f;
        #pragma unroll
        for (int gg = 0; gg < 8; ++gg) { lt0 += Lp[gg][r0]; lt1 += Lp[gg][r1]; }
        float x0 = pacc0 / lt0;
        float x1 = pacc1 / lt1;
        x0 = x0 > 0.f ? x0 : (__expf(x0) - 1.f);
        x1 = x1 > 0.f ? x1 : (__expf(x1) - 1.f);
        out[((size_t)b * NN + i0 + r0) * 64 + lane] = x0;
        out[((size_t)b * NN + i0 + r1) * 64 + lane] = x1;
    }
}

// ---------------------------------------------------------------------------
extern "C" void kernel_launch(void* const* d_in, const int* in_sizes, int n_in,
                              void* d_out, int out_size, void* d_ws, size_t ws_size,
                              hipStream_t stream) {
    (void)in_sizes; (void)n_in; (void)out_size; (void)ws_size;
    const float* h  = (const float*)d_in[0];
    const float* pm = (const float*)d_in[1];
    const float* sm = (const float*)d_in[2];
    const float* W  = (const float*)d_in[3];
    const float* R  = (const float*)d_in[4];
    const float* aq = (const float*)d_in[5];
    const float* ak = (const float*)d_in[6];
    const float* qb = (const float*)d_in[7];
    const float* op = (const float*)d_in[8];
    const int*   qm = (const int*)d_in[9];
    float* out = (float*)d_out;

    half_t* ws  = (half_t*)d_ws;
    half_t* Qw  = ws;                                 // 1 MB
    half_t* Kw  = ws + (size_t)BB * NN * 64;          // 1 MB
    half_t* WhJ = ws + (size_t)BB * NN * 64 * 2;      // 4 MB

    precompute_kernel<<<BB * NN / 8, 256, 0, stream>>>(h, W, R, aq, ak, Qw, Kw, WhJ);
    attn5_kernel<<<BB * (NN / 16), 512, 0, stream>>>(Qw, Kw, WhJ, pm, sm, qm, qb, op, out);
}